// Round 5
// baseline (1498.153 us; speedup 1.0000x reference)
//
#include <hip/hip_runtime.h>
#include <math.h>

#define BATCH 4
#define C 512
#define N 4096   // content spatial (64*64)
#define M 4096   // style spatial (64*64)
#define MSPLIT 4

typedef __attribute__((ext_vector_type(8))) short short8;
typedef __attribute__((ext_vector_type(8))) __bf16 bf16x8;
typedef __attribute__((ext_vector_type(4))) float f32x4;

static __device__ __forceinline__ unsigned short f2bf(float x) {
    unsigned u = __float_as_uint(x);
    u += 0x7fff + ((u >> 16) & 1);          // round-to-nearest-even
    return (unsigned short)(u >> 16);
}
static __device__ __forceinline__ float bf2f(unsigned short h) {
    return __uint_as_float(((unsigned)h) << 16);
}
static __device__ __forceinline__ f32x4 mfma_bf16(short8 a, short8 b, f32x4 c) {
    return __builtin_amdgcn_mfma_f32_16x16x32_bf16(
        __builtin_bit_cast(bf16x8, a), __builtin_bit_cast(bf16x8, b), c, 0, 0, 0);
}

// ---------------------------------------------------------------------------
// K0: split W (512x512 fp32) into bf16 hi/lo, once per call
// ---------------------------------------------------------------------------
__global__ __launch_bounds__(256) void wsplit_kernel(
    const float* __restrict__ W, unsigned short* __restrict__ hi,
    unsigned short* __restrict__ lo)
{
    int i = blockIdx.x * 256 + threadIdx.x;
    float v = W[i];
    unsigned short h = f2bf(v);
    hi[i] = h;
    lo[i] = f2bf(v - bf2f(h));
}

// ---------------------------------------------------------------------------
// K1a: MFMA linear for Fq/Gt: out[n][o] (hi/lo bf16), o fastest.
// block 64n x 64o, BK=32, waves 2x2 (wave tile 32n x 32o)
// ---------------------------------------------------------------------------
__global__ __launch_bounds__(256) void linear_fg_mfma(
    const float* __restrict__ in,                     // [C][N] batch slice
    const unsigned short* __restrict__ Whi, const unsigned short* __restrict__ Wlo,
    const float* __restrict__ bias,
    unsigned short* __restrict__ out_hi, unsigned short* __restrict__ out_lo)
{
    __shared__ float in_s[32][68];                    // [k][n] fp32
    __shared__ __align__(16) unsigned short wh_s[64][40];  // [o][k]
    __shared__ __align__(16) unsigned short wl_s[64][40];
    const int tid = threadIdx.x;
    const int n0 = blockIdx.x * 64, o0 = blockIdx.y * 64;
    const int w = tid >> 6, lane = tid & 63;
    const int wrow = w >> 1, wcol = w & 1;
    const int lr = lane & 15, q = lane >> 4;
    f32x4 acc[2][2];
    #pragma unroll
    for (int i = 0; i < 2; ++i)
        #pragma unroll
        for (int j = 0; j < 2; ++j) acc[i][j] = (f32x4){0.f, 0.f, 0.f, 0.f};

    for (int kc = 0; kc < C; kc += 32) {
        __syncthreads();
        #pragma unroll
        for (int it = 0; it < 2; ++it) {
            int idx = tid + it * 256;
            int k = idx >> 4, seg = idx & 15;
            *(float4*)&in_s[k][seg * 4] =
                *(const float4*)&in[(size_t)(kc + k) * N + n0 + seg * 4];
        }
        {
            int o = tid >> 2, sg = tid & 3;
            *(float4*)&wh_s[o][sg * 8] = *(const float4*)&Whi[(size_t)(o0 + o) * 512 + kc + sg * 8];
            *(float4*)&wl_s[o][sg * 8] = *(const float4*)&Wlo[(size_t)(o0 + o) * 512 + kc + sg * 8];
        }
        __syncthreads();
        short8 ah[2], al[2], bh[2], bl[2];
        #pragma unroll
        for (int i = 0; i < 2; ++i) {
            int n = wrow * 32 + i * 16 + lr;
            #pragma unroll
            for (int j = 0; j < 8; ++j) {
                float f = in_s[q * 8 + j][n];
                unsigned short h = f2bf(f);
                ah[i][j] = (short)h;
                al[i][j] = (short)f2bf(f - bf2f(h));
            }
        }
        #pragma unroll
        for (int j = 0; j < 2; ++j) {
            int o = wcol * 32 + j * 16 + lr;
            bh[j] = *(const short8*)&wh_s[o][q * 8];
            bl[j] = *(const short8*)&wl_s[o][q * 8];
        }
        #pragma unroll
        for (int i = 0; i < 2; ++i)
            #pragma unroll
            for (int j = 0; j < 2; ++j) {
                acc[i][j] = mfma_bf16(ah[i], bh[j], acc[i][j]);
                acc[i][j] = mfma_bf16(ah[i], bl[j], acc[i][j]);
                acc[i][j] = mfma_bf16(al[i], bh[j], acc[i][j]);
            }
    }
    #pragma unroll
    for (int i = 0; i < 2; ++i)
        #pragma unroll
        for (int j = 0; j < 2; ++j) {
            int o = o0 + wcol * 32 + j * 16 + lr;
            float bo = bias[o];
            #pragma unroll
            for (int r = 0; r < 4; ++r) {
                int n = n0 + wrow * 32 + i * 16 + q * 4 + r;
                float v = acc[i][j][r] + bo;
                unsigned short h = f2bf(v);
                out_hi[(size_t)n * 512 + o] = h;
                out_lo[(size_t)n * 512 + o] = f2bf(v - bf2f(h));
            }
        }
}

// ---------------------------------------------------------------------------
// K1b: MFMA linear for V: vhT[o][m], v2hT/v2lT = hi/lo of vh^2 (transposed
// output falls out of C/D layout: rows=o from A=W, cols=m from B=input)
// ---------------------------------------------------------------------------
__global__ __launch_bounds__(256) void linear_v_mfma(
    const float* __restrict__ in,                     // [C][M] batch slice
    const unsigned short* __restrict__ Whi, const unsigned short* __restrict__ Wlo,
    const float* __restrict__ bias,
    unsigned short* __restrict__ vhT, unsigned short* __restrict__ v2hT,
    unsigned short* __restrict__ v2lT)
{
    __shared__ float in_s[32][68];                    // [k][m]
    __shared__ __align__(16) unsigned short wh_s[64][40];
    __shared__ __align__(16) unsigned short wl_s[64][40];
    const int tid = threadIdx.x;
    const int m0 = blockIdx.x * 64, o0 = blockIdx.y * 64;
    const int w = tid >> 6, lane = tid & 63;
    const int wrow = w >> 1, wcol = w & 1;
    const int lr = lane & 15, q = lane >> 4;
    f32x4 acc[2][2];
    #pragma unroll
    for (int i = 0; i < 2; ++i)
        #pragma unroll
        for (int j = 0; j < 2; ++j) acc[i][j] = (f32x4){0.f, 0.f, 0.f, 0.f};

    for (int kc = 0; kc < C; kc += 32) {
        __syncthreads();
        #pragma unroll
        for (int it = 0; it < 2; ++it) {
            int idx = tid + it * 256;
            int k = idx >> 4, seg = idx & 15;
            *(float4*)&in_s[k][seg * 4] =
                *(const float4*)&in[(size_t)(kc + k) * N + m0 + seg * 4];
        }
        {
            int o = tid >> 2, sg = tid & 3;
            *(float4*)&wh_s[o][sg * 8] = *(const float4*)&Whi[(size_t)(o0 + o) * 512 + kc + sg * 8];
            *(float4*)&wl_s[o][sg * 8] = *(const float4*)&Wlo[(size_t)(o0 + o) * 512 + kc + sg * 8];
        }
        __syncthreads();
        short8 ah[2], al[2], bh[2], bl[2];
        #pragma unroll
        for (int i = 0; i < 2; ++i) {
            int o = wrow * 32 + i * 16 + lr;
            ah[i] = *(const short8*)&wh_s[o][q * 8];
            al[i] = *(const short8*)&wl_s[o][q * 8];
        }
        #pragma unroll
        for (int j = 0; j < 2; ++j) {
            int m = wcol * 32 + j * 16 + lr;
            #pragma unroll
            for (int t = 0; t < 8; ++t) {
                float f = in_s[q * 8 + t][m];
                unsigned short h = f2bf(f);
                bh[j][t] = (short)h;
                bl[j][t] = (short)f2bf(f - bf2f(h));
            }
        }
        #pragma unroll
        for (int i = 0; i < 2; ++i)
            #pragma unroll
            for (int j = 0; j < 2; ++j) {
                acc[i][j] = mfma_bf16(ah[i], bh[j], acc[i][j]);
                acc[i][j] = mfma_bf16(ah[i], bl[j], acc[i][j]);
                acc[i][j] = mfma_bf16(al[i], bh[j], acc[i][j]);
            }
    }
    #pragma unroll
    for (int i = 0; i < 2; ++i)
        #pragma unroll
        for (int r = 0; r < 4; ++r) {
            int o = o0 + wrow * 32 + i * 16 + q * 4 + r;
            float bo = bias[o];
            #pragma unroll
            for (int j = 0; j < 2; ++j) {
                int m = m0 + wcol * 32 + j * 16 + lr;
                float v = acc[i][j][r] + bo;
                unsigned short vh = f2bf(v);
                float vhf = bf2f(vh);
                float vsq = vhf * vhf;
                unsigned short v2h = f2bf(vsq);
                unsigned short v2l = f2bf(vsq - bf2f(v2h));
                size_t off = (size_t)o * M + m;
                vhT[off] = vh;
                v2hT[off] = v2h;
                v2lT[off] = v2l;
            }
        }
}

// ---------------------------------------------------------------------------
// K2: logits MFMA, A-direct-from-global (hi/lo), B staged in LDS.
// block tile 128n x 128m, BK=32, waves 2x2, wave tile 64x64
// ---------------------------------------------------------------------------
__global__ __launch_bounds__(256) void logits_mfma_kernel(
    const unsigned short* __restrict__ Ah, const unsigned short* __restrict__ Al,
    const unsigned short* __restrict__ Bh, const unsigned short* __restrict__ Bl,
    float* __restrict__ S)
{
    __shared__ __align__(16) unsigned short Bh_s[128 * 40];
    __shared__ __align__(16) unsigned short Bl_s[128 * 40];
    const int tid = threadIdx.x;
    const int n0 = blockIdx.y * 128, m0 = blockIdx.x * 128;
    const int w = tid >> 6, lane = tid & 63;
    const int wrow = w >> 1, wcol = w & 1;
    const int lr = lane & 15, q = lane >> 4;

    const unsigned short* ahp[4];
    const unsigned short* alp[4];
    #pragma unroll
    for (int i = 0; i < 4; ++i) {
        size_t ro = (size_t)(n0 + wrow * 64 + i * 16 + lr) * C + q * 8;
        ahp[i] = Ah + ro;
        alp[i] = Al + ro;
    }

    f32x4 acc[4][4];
    #pragma unroll
    for (int i = 0; i < 4; ++i)
        #pragma unroll
        for (int j = 0; j < 4; ++j)
            acc[i][j] = (f32x4){0.f, 0.f, 0.f, 0.f};

    for (int kc = 0; kc < C; kc += 32) {
        __syncthreads();
        #pragma unroll
        for (int it = 0; it < 2; ++it) {
            int idx = tid + it * 256;
            int row = idx >> 2, seg = idx & 3;
            int ldso = row * 40 + seg * 8;
            int go = kc + seg * 8;
            *(float4*)&Bh_s[ldso] = *(const float4*)&Bh[(size_t)(m0 + row) * C + go];
            *(float4*)&Bl_s[ldso] = *(const float4*)&Bl[(size_t)(m0 + row) * C + go];
        }
        // A fragments direct from global (independent of LDS; issue pre-barrier)
        short8 ah[4], al[4];
        #pragma unroll
        for (int i = 0; i < 4; ++i) {
            ah[i] = *(const short8*)(ahp[i] + kc);
            al[i] = *(const short8*)(alp[i] + kc);
        }
        __syncthreads();
        short8 bh[4], bl[4];
        #pragma unroll
        for (int j = 0; j < 4; ++j) {
            int co = (wcol * 64 + j * 16 + lr) * 40 + q * 8;
            bh[j] = *(const short8*)&Bh_s[co];
            bl[j] = *(const short8*)&Bl_s[co];
        }
        #pragma unroll
        for (int i = 0; i < 4; ++i)
            #pragma unroll
            for (int j = 0; j < 4; ++j) {
                acc[i][j] = mfma_bf16(ah[i], bh[j], acc[i][j]);
                acc[i][j] = mfma_bf16(ah[i], bl[j], acc[i][j]);
                acc[i][j] = mfma_bf16(al[i], bh[j], acc[i][j]);
            }
    }
    #pragma unroll
    for (int i = 0; i < 4; ++i) {
        int nb = n0 + wrow * 64 + i * 16 + q * 4;
        #pragma unroll
        for (int j = 0; j < 4; ++j) {
            int m = m0 + wcol * 64 + j * 16 + lr;
            #pragma unroll
            for (int r = 0; r < 4; ++r)
                S[(size_t)(nb + r) * M + m] = acc[i][j][r];
        }
    }
}

// ---------------------------------------------------------------------------
// K3: row softmax -> bf16 P, rsum = sum of the ROUNDED p (consistency!)
// ---------------------------------------------------------------------------
__global__ __launch_bounds__(256) void rowstat_p_kernel(
    const float* __restrict__ S, unsigned short* __restrict__ P,
    float* __restrict__ rsum)
{
    const int n = blockIdx.x;
    const int tid = threadIdx.x;
    const float* row = S + (size_t)n * M;
    float v[16];
    #pragma unroll
    for (int i = 0; i < 16; ++i) v[i] = row[tid + i * 256];
    float lm = -INFINITY;
    #pragma unroll
    for (int i = 0; i < 16; ++i) lm = fmaxf(lm, v[i]);
    #pragma unroll
    for (int off = 32; off > 0; off >>= 1) lm = fmaxf(lm, __shfl_xor(lm, off, 64));
    __shared__ float red[4];
    __shared__ float redsum[4];
    const int wid = tid >> 6, lane = tid & 63;
    if (lane == 0) red[wid] = lm;
    __syncthreads();
    const float rm = fmaxf(fmaxf(red[0], red[1]), fmaxf(red[2], red[3]));
    float ls = 0.f;
    unsigned short* prow = P + (size_t)n * M;
    #pragma unroll
    for (int i = 0; i < 16; ++i) {
        float p = __expf(v[i] - rm);
        unsigned short pb = f2bf(p);
        prow[tid + i * 256] = pb;
        ls += bf2f(pb);
    }
    #pragma unroll
    for (int off = 32; off > 0; off >>= 1) ls += __shfl_xor(ls, off, 64);
    if (lane == 0) redsum[wid] = ls;
    __syncthreads();
    if (tid == 0) rsum[n] = redsum[0] + redsum[1] + redsum[2] + redsum[3];
}

// ---------------------------------------------------------------------------
// K4: apply partial, ZERO-LDS: all fragments direct from global (P and V^T
// are contiguous along the MFMA K dim; q-quads share 64B lines). No barriers
// in the K-loop; 2-deep register double-buffer hides L1/L2 latency.
// Grid (C/64, N/128, MSPLIT); partials alias the dead S buffer.
// ---------------------------------------------------------------------------
__global__ __launch_bounds__(256) void apply_partial_kernel(
    const unsigned short* __restrict__ P, const unsigned short* __restrict__ VhT,
    const unsigned short* __restrict__ V2hT, const unsigned short* __restrict__ V2lT,
    float* __restrict__ accm_p, float* __restrict__ acc2_p)
{
    const int tid = threadIdx.x;
    const int c0 = blockIdx.x * 64, n0 = blockIdx.y * 128;
    const int z = blockIdx.z;
    const int w = tid >> 6, lane = tid & 63;
    const int wrow = w >> 1, wcol = w & 1;
    const int lr = lane & 15, q = lane >> 4;
    const int mbeg = z * (M / MSPLIT);

    const unsigned short* ap[4];
    #pragma unroll
    for (int i = 0; i < 4; ++i)
        ap[i] = P + (size_t)(n0 + wrow * 64 + i * 16 + lr) * M + mbeg + q * 8;
    const unsigned short* bp[6];
    #pragma unroll
    for (int j = 0; j < 2; ++j) {
        size_t ro = (size_t)(c0 + wcol * 32 + j * 16 + lr) * M + mbeg + q * 8;
        bp[j]     = VhT  + ro;
        bp[2 + j] = V2hT + ro;
        bp[4 + j] = V2lT + ro;
    }

    f32x4 accm[4][2], acc2[4][2];
    #pragma unroll
    for (int i = 0; i < 4; ++i)
        #pragma unroll
        for (int j = 0; j < 2; ++j) {
            accm[i][j] = (f32x4){0.f, 0.f, 0.f, 0.f};
            acc2[i][j] = (f32x4){0.f, 0.f, 0.f, 0.f};
        }

    auto do_mfma = [&](const short8 (&a)[4], const short8 (&b)[6]) {
        #pragma unroll
        for (int i = 0; i < 4; ++i)
            #pragma unroll
            for (int j = 0; j < 2; ++j) {
                accm[i][j] = mfma_bf16(a[i], b[j],     accm[i][j]);
                acc2[i][j] = mfma_bf16(a[i], b[2 + j], acc2[i][j]);
                acc2[i][j] = mfma_bf16(a[i], b[4 + j], acc2[i][j]);
            }
    };

    short8 fa[4], fb[6], ga[4], gb[6];
    #pragma unroll
    for (int i = 0; i < 4; ++i) fa[i] = *(const short8*)ap[i];
    #pragma unroll
    for (int j = 0; j < 6; ++j) fb[j] = *(const short8*)bp[j];

    // 32 K-steps of 32: step 0 preloaded; 15 double-iterations; 2-step tail
    #pragma unroll 1
    for (int it = 0; it < 15; ++it) {
        const int off1 = it * 64 + 32;
        const int off2 = it * 64 + 64;
        #pragma unroll
        for (int i = 0; i < 4; ++i) ga[i] = *(const short8*)(ap[i] + off1);
        #pragma unroll
        for (int j = 0; j < 6; ++j) gb[j] = *(const short8*)(bp[j] + off1);
        do_mfma(fa, fb);
        #pragma unroll
        for (int i = 0; i < 4; ++i) fa[i] = *(const short8*)(ap[i] + off2);
        #pragma unroll
        for (int j = 0; j < 6; ++j) fb[j] = *(const short8*)(bp[j] + off2);
        do_mfma(ga, gb);
    }
    #pragma unroll
    for (int i = 0; i < 4; ++i) ga[i] = *(const short8*)(ap[i] + 992);
    #pragma unroll
    for (int j = 0; j < 6; ++j) gb[j] = *(const short8*)(bp[j] + 992);
    do_mfma(fa, fb);   // step at offset 960
    do_mfma(ga, gb);   // step at offset 992

    const size_t pbase = (size_t)z * N * C;
    #pragma unroll
    for (int i = 0; i < 4; ++i) {
        int nb = n0 + wrow * 64 + i * 16 + q * 4;
        #pragma unroll
        for (int j = 0; j < 2; ++j) {
            int c = c0 + wcol * 32 + j * 16 + lr;
            #pragma unroll
            for (int r = 0; r < 4; ++r) {
                size_t off = pbase + (size_t)(nb + r) * C + c;
                accm_p[off] = accm[i][j][r];
                acc2_p[off] = acc2[i][j][r];
            }
        }
    }
}

// ---------------------------------------------------------------------------
// K4b: combine partials -> mean/std (fp32). One float4 of c per thread.
// ---------------------------------------------------------------------------
__global__ __launch_bounds__(256) void combine_kernel(
    const float* __restrict__ accm_p, const float* __restrict__ acc2_p,
    const float* __restrict__ rsum, float* __restrict__ meanw,
    float* __restrict__ stdw)
{
    const size_t idx = ((size_t)blockIdx.x * 256 + threadIdx.x) * 4;
    const int n = (int)(idx >> 9);        // /C (C=512)
    const float inv = 1.0f / rsum[n];
    float sm[4] = {0.f, 0.f, 0.f, 0.f}, s2[4] = {0.f, 0.f, 0.f, 0.f};
    #pragma unroll
    for (int z = 0; z < MSPLIT; ++z) {
        float4 a = *(const float4*)&accm_p[(size_t)z * N * C + idx];
        float4 b = *(const float4*)&acc2_p[(size_t)z * N * C + idx];
        sm[0] += a.x; sm[1] += a.y; sm[2] += a.z; sm[3] += a.w;
        s2[0] += b.x; s2[1] += b.y; s2[2] += b.z; s2[3] += b.w;
    }
    float4 mnv, sdv;
    float* mp = (float*)&mnv;
    float* sp = (float*)&sdv;
    #pragma unroll
    for (int k = 0; k < 4; ++k) {
        float mn = sm[k] * inv;
        float m2 = s2[k] * inv;
        mp[k] = mn;
        sp[k] = sqrtf(fmaxf(m2 - mn * mn, 0.f));
    }
    *(float4*)&meanw[idx] = mnv;
    *(float4*)&stdw[idx]  = sdv;
}

// ---------------------------------------------------------------------------
// K5: instance-norm stats per channel (fp32)
// ---------------------------------------------------------------------------
__global__ __launch_bounds__(256) void mvn_kernel(
    const float* __restrict__ content, float* __restrict__ mu, float* __restrict__ rstd)
{
    const int c = blockIdx.x;
    const int tid = threadIdx.x;
    const float* row = content + (size_t)c * N;
    float s = 0.f, ss = 0.f;
    for (int i = tid; i < N; i += 256) {
        float v = row[i];
        s += v;
        ss = fmaf(v, v, ss);
    }
    #pragma unroll
    for (int off = 32; off > 0; off >>= 1) {
        s  += __shfl_xor(s,  off, 64);
        ss += __shfl_xor(ss, off, 64);
    }
    __shared__ float rs[4], rss[4];
    const int wid = tid >> 6, lane = tid & 63;
    if (lane == 0) { rs[wid] = s; rss[wid] = ss; }
    __syncthreads();
    if (tid == 0) {
        float st = rs[0] + rs[1] + rs[2] + rs[3];
        float sst = rss[0] + rss[1] + rss[2] + rss[3];
        float m = st / (float)N;
        float var = (sst - st * st / (float)N) / (float)(N - 1);
        mu[c] = m;
        rstd[c] = rsqrtf(var + 1e-5f);
    }
}

// ---------------------------------------------------------------------------
// K6: final combine (fp32)
// ---------------------------------------------------------------------------
__global__ __launch_bounds__(256) void final_kernel(
    const float* __restrict__ content, const float* __restrict__ meanw,
    const float* __restrict__ stdw, const float* __restrict__ mu,
    const float* __restrict__ rstd, float* __restrict__ out)
{
    __shared__ float mn_s[32][33], sd_s[32][33];
    const int tid = threadIdx.x;
    const int n0 = blockIdx.x * 32;
    const int c0 = blockIdx.y * 32;
    const int tx = tid & 31, ty = tid >> 5;
    #pragma unroll
    for (int i = 0; i < 4; ++i) {
        int n = ty + i * 8;
        mn_s[tx][n] = meanw[(size_t)(n0 + n) * C + c0 + tx];
        sd_s[tx][n] = stdw [(size_t)(n0 + n) * C + c0 + tx];
    }
    __syncthreads();
    #pragma unroll
    for (int i = 0; i < 4; ++i) {
        int c = ty + i * 8;
        float m = mu[c0 + c], r = rstd[c0 + c];
        size_t off = (size_t)(c0 + c) * N + n0 + tx;
        float x = content[off];
        out[off] = sd_s[c][tx] * (x - m) * r + mn_s[c][tx];
    }
}

// ---------------------------------------------------------------------------
extern "C" void kernel_launch(void* const* d_in, const int* in_sizes, int n_in,
                              void* d_out, int out_size, void* d_ws, size_t ws_size,
                              hipStream_t stream)
{
    const float* content = (const float*)d_in[0];
    const float* style   = (const float*)d_in[1];
    const float* ckey    = (const float*)d_in[2];
    const float* skey    = (const float*)d_in[3];
    const float* Wf      = (const float*)d_in[4];
    const float* bf      = (const float*)d_in[5];
    const float* Wg      = (const float*)d_in[6];
    const float* bg      = (const float*)d_in[7];
    const float* Wh      = (const float*)d_in[8];
    const float* bh      = (const float*)d_in[9];
    float* out = (float*)d_out;

    const size_t sz_w  = (size_t)512 * 512 * 2;      // one W half
    const size_t sz_S  = (size_t)N * M * 4;          // 64 MB (aliased by partials)
    const size_t sz_FG = (size_t)N * C * 2;
    const size_t sz_P  = (size_t)N * M * 2;
    const size_t sz_V  = (size_t)C * M * 2;

    char* p = (char*)d_ws;
    auto alloc = [&](size_t bytes) {
        char* r = p;
        p += (bytes + 255) & ~(size_t)255;
        return r;
    };
    unsigned short* WfH = (unsigned short*)alloc(sz_w);
    unsigned short* WfL = (unsigned short*)alloc(sz_w);
    unsigned short* WgH = (unsigned short*)alloc(sz_w);
    unsigned short* WgL = (unsigned short*)alloc(sz_w);
    unsigned short* WhH = (unsigned short*)alloc(sz_w);
    unsigned short* WhL = (unsigned short*)alloc(sz_w);
    float* S = (float*)alloc(sz_S);                  // also: partial accm/acc2
    unsigned short* Fh = (unsigned short*)alloc(sz_FG);
    unsigned short* Fl = (unsigned short*)alloc(sz_FG);
    unsigned short* Gh = (unsigned short*)alloc(sz_FG);
    unsigned short* Gl = (unsigned short*)alloc(sz_FG);
    unsigned short* P    = (unsigned short*)alloc(sz_P);
    unsigned short* VhT  = (unsigned short*)alloc(sz_V);
    unsigned short* V2hT = (unsigned short*)alloc(sz_V);
    unsigned short* V2lT = (unsigned short*)alloc(sz_V);
    float* rsum  = (float*)alloc((size_t)N * 4);
    float* meanw = (float*)alloc((size_t)N * C * 4);
    float* stdw  = (float*)alloc((size_t)N * C * 4);
    float* mu    = (float*)alloc((size_t)C * 4);
    float* rstd  = (float*)alloc((size_t)C * 4);

    // partials alias S (dead between rowstat and next batch's logits)
    float* accm_p = S;
    float* acc2_p = S + (size_t)MSPLIT * N * C;

    wsplit_kernel<<<dim3(1024), 256, 0, stream>>>(Wf, WfH, WfL);
    wsplit_kernel<<<dim3(1024), 256, 0, stream>>>(Wg, WgH, WgL);
    wsplit_kernel<<<dim3(1024), 256, 0, stream>>>(Wh, WhH, WhL);

    for (int b = 0; b < BATCH; ++b) {
        const size_t fo = (size_t)b * C * N;
        linear_fg_mfma<<<dim3(N / 64, C / 64), 256, 0, stream>>>(ckey + fo, WfH, WfL, bf, Fh, Fl);
        linear_fg_mfma<<<dim3(M / 64, C / 64), 256, 0, stream>>>(skey + fo, WgH, WgL, bg, Gh, Gl);
        linear_v_mfma<<<dim3(M / 64, C / 64), 256, 0, stream>>>(style + fo, WhH, WhL, bh,
                                                                VhT, V2hT, V2lT);
        logits_mfma_kernel<<<dim3(M / 128, N / 128), 256, 0, stream>>>(Fh, Fl, Gh, Gl, S);
        rowstat_p_kernel<<<dim3(N), 256, 0, stream>>>(S, P, rsum);
        apply_partial_kernel<<<dim3(C / 64, N / 128, MSPLIT), 256, 0, stream>>>(
            P, VhT, V2hT, V2lT, accm_p, acc2_p);
        combine_kernel<<<dim3(N * C / 1024), 256, 0, stream>>>(
            accm_p, acc2_p, rsum, meanw, stdw);
        mvn_kernel<<<dim3(C), 256, 0, stream>>>(content + fo, mu, rstd);
        final_kernel<<<dim3(N / 32, C / 32), 256, 0, stream>>>(
            content + fo, meanw, stdw, mu, rstd, out + fo);
    }
}